// Round 1
// baseline (1136.720 us; speedup 1.0000x reference)
//
#include <hip/hip_runtime.h>
#include <hip/hip_cooperative_groups.h>
#include <math.h>

namespace cg = cooperative_groups;

#define NGRAPH 32
#define CAP 10240        // edge capacity per bucket (mean 8163, ~23 sigma)
#define EPT 8            // edges per thread in part phase (was 24 -> more blocks, more TLP)
#define EPB (256 * EPT)  // 2048 edges per partition chunk
#define GRID 1024
#define BLK 256

// ---------------- shared-memory union across phases (12.3 KB max) ----------------
struct SMemPart {
    unsigned int ldsbuf[EPB];            // 8 KB
    int hist[256], lofs[256], lcur[256], base[256];  // 4 KB
};
struct SMemBucket {
    int cnt[256], lofs[256], lcur[256];
    float cs[NGRAPH];
};
struct SMemChain {
    float v4[512];
};
struct SMemMlp {
    float pl[128], red[128], r4[512];
    float cnts[NGRAPH];
};
union SMem {
    SMemPart   part;
    SMemBucket bucket;
    SMemChain  chain;
    SMemMlp    mlp;
};

// ---------------- one hop, 16 lanes per node, grid-strided over 16-node tiles ----------------
template <int WRITE_Q>
__device__ __forceinline__ void hop_phase(
        const float2* __restrict__ qin, float2* __restrict__ outv,
        const unsigned short* __restrict__ csr,
        const int* __restrict__ offs, const int* __restrict__ deg,
        const float* __restrict__ dinv, int N, int ntiles,
        int bid, int nblk, int tid) {
    int lane = tid & 15;
    int sub  = tid >> 4;
    for (int t = bid; t < ntiles; t += nblk) {
        int node = t * 16 + sub;
        if (node >= N) continue;
        int e = offs[node], ne = deg[node];   // e even; slot even-padded with sentinel
        float sx = 0.0f, su = 0.0f;
        for (int j = 2 * lane; j < ne; j += 32) {
            ushort2 c = *(const ushort2*)&csr[e + j];   // pad entry -> qin[N] == (0,0)
            float2 a = qin[c.x];
            float2 b = qin[c.y];
            sx += a.x + b.x;
            su += a.y + b.y;
        }
#pragma unroll
        for (int m = 8; m > 0; m >>= 1) {
            sx += __shfl_xor(sx, m);
            su += __shfl_xor(su, m);
        }
        if (lane == 0) {
            float2 qs = qin[node];
            float dv = dinv[node];
            float px = dv * (sx + qs.x), pu = dv * (su + qs.y);
            if (WRITE_Q) outv[node] = make_float2(px * dv, pu * dv);
            else         outv[node] = make_float2(px, pu);
        }
    }
}

// ---------------- fused cooperative pipeline ----------------
__global__ __launch_bounds__(BLK, 4) void fused(
        const int* __restrict__ src, const int* __restrict__ dst,
        const float* __restrict__ x, const int* __restrict__ batch,
        const float* __restrict__ lin_w, const float* __restrict__ lin_b,
        const float* __restrict__ gcn_w, const float* __restrict__ gcn_b,
        const float* __restrict__ r1_w, const float* __restrict__ r1_b,
        const float* __restrict__ r2_w, const float* __restrict__ r2_b,
        float* __restrict__ out,
        float2* __restrict__ q0, float2* __restrict__ q1,
        float2* __restrict__ q2, float2* __restrict__ p3,
        unsigned int* __restrict__ packed, int* __restrict__ offs,
        int* __restrict__ deg, float* __restrict__ dinv,
        int* __restrict__ gcursor, float* __restrict__ S,
        float* __restrict__ chainv, unsigned short* __restrict__ csr,
        int N, int E) {
    cg::grid_group grid = cg::this_grid();
    __shared__ SMem sm;
    const int tid  = threadIdx.x;
    const int bid  = blockIdx.x;
    const int nblk = gridDim.x;

    // ======== phase P: edge partition (blocks 0..nblk-2) || weight chain (last block) ========
    const int nchunk = (E + EPB - 1) / EPB;
    if (bid == nblk - 1) {
        // chain: 4 vectors of 128 through 3 layers; W read straight from global (L2)
        float* v4 = sm.chain.v4;
        int j = tid & 127, gg = tid >> 7;   // gg in {0,1}; thread owns vecs {gg, gg+2}
        if (tid < 128) {
            v4[tid]       = lin_w[tid];
            v4[128 + tid] = lin_b[tid];
            v4[256 + tid] = gcn_b[tid];        // b1
            v4[384 + tid] = gcn_b[128 + tid];  // b2
        }
        __syncthreads();
        for (int l = 0; l < 3; l++) {
            const float* W = gcn_w + l * 128 * 128;
            float a0 = 0.f, a1 = 0.f;
#pragma unroll 4
            for (int k = 0; k < 128; k++) {
                float w = W[k * 128 + j];      // coalesced across j
                a0 += v4[gg * 128 + k] * w;
                a1 += v4[(gg + 2) * 128 + k] * w;
            }
            __syncthreads();
            v4[gg * 128 + j] = a0;             // vec0 (w-chain), vec1 (b-chain): always
            bool upd = (gg == 0) ? (l >= 1) : (l >= 2);  // vec2 from l>=1, vec3 from l>=2
            if (upd) v4[(gg + 2) * 128 + j] = a1;
            __syncthreads();
        }
        chainv[tid]       = v4[tid];
        chainv[256 + tid] = v4[256 + tid];
    } else {
        for (int c = bid; c < nchunk; c += nblk - 1) {
            int e0 = c * EPB;
            sm.part.hist[tid] = 0;
            __syncthreads();
            int d_[EPT], s_[EPT];
#pragma unroll
            for (int cc = 0; cc < EPT / 4; cc++) {
                int e = e0 + cc * 1024 + (tid << 2);
                if (e + 3 < E) {
                    int4 dv = *(const int4*)&dst[e];
                    int4 sv = *(const int4*)&src[e];
                    d_[4*cc+0] = dv.x; d_[4*cc+1] = dv.y; d_[4*cc+2] = dv.z; d_[4*cc+3] = dv.w;
                    s_[4*cc+0] = sv.x; s_[4*cc+1] = sv.y; s_[4*cc+2] = sv.z; s_[4*cc+3] = sv.w;
                    atomicAdd(&sm.part.hist[dv.x >> 8], 1);
                    atomicAdd(&sm.part.hist[dv.y >> 8], 1);
                    atomicAdd(&sm.part.hist[dv.z >> 8], 1);
                    atomicAdd(&sm.part.hist[dv.w >> 8], 1);
                } else {
#pragma unroll
                    for (int k = 0; k < 4; k++) {
                        int ee = e + k;
                        if (ee < E) {
                            d_[4*cc+k] = dst[ee]; s_[4*cc+k] = src[ee];
                            atomicAdd(&sm.part.hist[d_[4*cc+k] >> 8], 1);
                        } else {
                            d_[4*cc+k] = -1;
                        }
                    }
                }
            }
            __syncthreads();
            int v = sm.part.hist[tid];
            sm.part.lofs[tid] = v;
            __syncthreads();
            for (int off = 1; off < 256; off <<= 1) {
                int t = (tid >= off) ? sm.part.lofs[tid - off] : 0;
                __syncthreads();
                sm.part.lofs[tid] += t;
                __syncthreads();
            }
            int total = sm.part.lofs[255];
            int excl  = sm.part.lofs[tid] - v;
            __syncthreads();               // all reads of lofs done before overwrite
            sm.part.lofs[tid] = excl;
            sm.part.lcur[tid] = excl;
            if (v > 0) sm.part.base[tid] = tid * CAP + atomicAdd(&gcursor[tid], v);
            __syncthreads();
#pragma unroll
            for (int cc = 0; cc < EPT; cc++) {
                int dd = d_[cc];
                if (dd >= 0) {
                    int bk = dd >> 8;
                    int slot = atomicAdd(&sm.part.lcur[bk], 1);
                    sm.part.ldsbuf[slot] = ((unsigned int)bk << 24) | ((unsigned int)s_[cc] << 8)
                                         | (unsigned int)(dd & 255);
                }
            }
            __syncthreads();
            for (int i = tid; i < total; i += BLK) {
                unsigned int w = sm.part.ldsbuf[i];
                int bk = w >> 24;
                packed[sm.part.base[bk] + (i - sm.part.lofs[bk])] = w & 0xFFFFFFu;
            }
            __syncthreads();               // smem reuse guard for next chunk
        }
    }
    __threadfence();
    grid.sync();

    // ======== phase B: per-bucket CSR build + deg/dinv/q0/counts ========
    const int NB = (N + 255) >> 8;
    for (int b = bid; b < NB; b += nblk) {
        int start = b * CAP;
        int end = start + gcursor[b];
        sm.bucket.cnt[tid] = 0;
        if (tid < NGRAPH) sm.bucket.cs[tid] = 0.f;
        __syncthreads();
        for (int e = start + tid; e < end; e += BLK)
            atomicAdd(&sm.bucket.cnt[packed[e] & 255], 1);
        __syncthreads();
        int v = sm.bucket.cnt[tid];
        int vp = (v + 1) & ~1;            // pad each node's slot to even length
        sm.bucket.lofs[tid] = vp;
        __syncthreads();
        for (int off = 1; off < 256; off <<= 1) {
            int t = (tid >= off) ? sm.bucket.lofs[tid - off] : 0;
            __syncthreads();
            sm.bucket.lofs[tid] += t;
            __syncthreads();
        }
        int excl = sm.bucket.lofs[tid] - vp;
        sm.bucket.lcur[tid] = excl;
        int node = b * 256 + tid;
        if (node < N) {
            deg[node] = v;
            offs[node] = start + excl;
            float dv = rsqrtf((float)(v + 1));   // +1 self loop
            dinv[node] = dv;
            q0[node] = make_float2(x[node] * dv, dv);
            atomicAdd(&sm.bucket.cs[batch[node]], 1.f);
            if (v & 1) csr[start + excl + v] = (unsigned short)N;  // sentinel -> q[N]=(0,0)
        }
        if (b == 0 && tid == 0) {
            q0[N] = make_float2(0.f, 0.f);
            q1[N] = make_float2(0.f, 0.f);
            q2[N] = make_float2(0.f, 0.f);
        }
        __syncthreads();
        for (int e = start + tid; e < end; e += BLK) {
            unsigned int p = packed[e];
            int pos = start + atomicAdd(&sm.bucket.lcur[p & 255], 1);
            csr[pos] = (unsigned short)(p >> 8);
        }
        if (tid < NGRAPH && sm.bucket.cs[tid] != 0.f) atomicAdd(&S[tid], sm.bucket.cs[tid]);
        __syncthreads();
    }
    __threadfence();
    grid.sync();

    // ======== phases H1..H3: three hops ========
    const int ntiles = (N + 15) >> 4;
    hop_phase<1>(q0, q1, csr, offs, deg, dinv, N, ntiles, bid, nblk, tid);
    __threadfence();
    grid.sync();
    hop_phase<1>(q1, q2, csr, offs, deg, dinv, N, ntiles, bid, nblk, tid);
    __threadfence();
    grid.sync();
    hop_phase<0>(q2, p3, csr, offs, deg, dinv, N, ntiles, bid, nblk, tid);
    __threadfence();
    grid.sync();

    // ======== phase M: per-graph readout + MLP (blocks 0..31) ========
    if (bid < NGRAPH) {
        int g = bid;
        if (tid < NGRAPH) sm.mlp.cnts[tid] = S[tid];
        __syncthreads();
        int r0 = 0;
        for (int i = 0; i < g; i++) r0 += (int)sm.mlp.cnts[i];
        int cnt = (int)sm.mlp.cnts[g];
        int r1e = r0 + cnt;
        float su1 = 0.f, su2 = 0.f, su3 = 0.f, sv3 = 0.f;
        for (int n = r0 + tid; n < r1e; n += BLK) {
            float inv = 1.0f / dinv[n];
            su1 += q1[n].y * inv;
            su2 += q2[n].y * inv;
            float2 p = p3[n];
            su3 += p.y; sv3 += p.x;
        }
#pragma unroll
        for (int m = 32; m > 0; m >>= 1) {
            su1 += __shfl_xor(su1, m);
            su2 += __shfl_xor(su2, m);
            su3 += __shfl_xor(su3, m);
            sv3 += __shfl_xor(sv3, m);
        }
        int wv = tid >> 6;
        if ((tid & 63) == 0) {
            sm.mlp.r4[wv] = su1; sm.mlp.r4[4 + wv] = su2;
            sm.mlp.r4[8 + wv] = su3; sm.mlp.r4[12 + wv] = sv3;
        }
        __syncthreads();
        su1 = sm.mlp.r4[0] + sm.mlp.r4[1] + sm.mlp.r4[2] + sm.mlp.r4[3];
        su2 = sm.mlp.r4[4] + sm.mlp.r4[5] + sm.mlp.r4[6] + sm.mlp.r4[7];
        su3 = sm.mlp.r4[8] + sm.mlp.r4[9] + sm.mlp.r4[10] + sm.mlp.r4[11];
        sv3 = sm.mlp.r4[12] + sm.mlp.r4[13] + sm.mlp.r4[14] + sm.mlp.r4[15];
        const float* b3 = gcn_b + 2 * 128;
        if (tid < 128)
            sm.mlp.pl[tid] = sv3 * chainv[tid] + su3 * chainv[128 + tid]
                           + su2 * chainv[256 + tid] + su1 * chainv[384 + tid]
                           + (float)cnt * b3[tid];
        __syncthreads();
        int j = tid & 127, half = tid >> 7;
        float acc = 0.f;
#pragma unroll 8
        for (int kk = 0; kk < 64; kk++) {
            int k = half * 64 + kk;
            acc += sm.mlp.pl[k] * r1_w[k * 128 + j];   // coalesced, L2-resident
        }
        sm.mlp.r4[half * 128 + j] = acc;
        __syncthreads();
        if (tid < 128) {
            float a = sm.mlp.r4[tid] + sm.mlp.r4[128 + tid] + r1_b[tid];
            sm.mlp.red[tid] = tanhf(a) * r2_w[tid];
        }
        __syncthreads();
        for (int sft = 64; sft > 0; sft >>= 1) {
            if (tid < sft) sm.mlp.red[tid] += sm.mlp.red[tid + sft];
            __syncthreads();
        }
        if (tid == 0) out[g] = sm.mlp.red[0] + r2_b[0];
    }
}

extern "C" void kernel_launch(void* const* d_in, const int* in_sizes, int n_in,
                              void* d_out, int out_size, void* d_ws, size_t ws_size,
                              hipStream_t stream) {
    const float* x     = (const float*)d_in[0];
    const int*   eidx  = (const int*)d_in[1];
    const int*   batch = (const int*)d_in[2];
    const float* lin_w = (const float*)d_in[3];
    const float* lin_b = (const float*)d_in[4];
    const float* gcn_w = (const float*)d_in[5];
    const float* gcn_b = (const float*)d_in[6];
    const float* r1_w  = (const float*)d_in[7];
    const float* r1_b  = (const float*)d_in[8];
    const float* r2_w  = (const float*)d_in[9];
    const float* r2_b  = (const float*)d_in[10];
    float* out = (float*)d_out;

    int N = in_sizes[0];
    int E = in_sizes[1] / 2;
    const int* src = eidx;
    const int* dst = eidx + E;

    // workspace layout: 8B-aligned types first, 4B, then 2B csr last
    char* w = (char*)d_ws;
    float2* q0      = (float2*)w; w += (size_t)(N + 2) * 8;
    float2* q1      = (float2*)w; w += (size_t)(N + 2) * 8;
    float2* q2      = (float2*)w; w += (size_t)(N + 2) * 8;
    float2* p3      = (float2*)w; w += (size_t)(N + 2) * 8;
    unsigned int* packed = (unsigned int*)w; w += (size_t)256 * CAP * 4;
    int*    offs    = (int*)w;    w += (size_t)N * 4;
    int*    deg     = (int*)w;    w += (size_t)N * 4;
    float*  dinv    = (float*)w;  w += (size_t)N * 4;
    int*    gcursor = (int*)w;    w += 256 * 4;
    float*  S       = (float*)w;  w += 64 * 4;
    float*  chainv  = (float*)w;  w += 512 * 4;
    unsigned short* csr = (unsigned short*)w; w += (size_t)256 * CAP * 2 + 256;

    // single memset covers gcursor (1024 B) + S (256 B), contiguous
    hipMemsetAsync(gcursor, 0, 256 * 4 + 64 * 4, stream);

    // co-residency-safe grid size (cached after first call)
    static int s_grid = 0;
    if (s_grid == 0) {
        int dev = 0, bpc = 0;
        hipGetDevice(&dev);
        hipDeviceProp_t prop;
        hipGetDeviceProperties(&prop, dev);
        hipOccupancyMaxActiveBlocksPerMultiprocessor(&bpc, fused, BLK, 0);
        long cap = (long)bpc * prop.multiProcessorCount;
        int g = (cap < GRID) ? (int)cap : GRID;
        if (g < 64) g = 64;
        s_grid = g;
    }

    void* kargs[] = { (void*)&src, (void*)&dst, (void*)&x, (void*)&batch,
                      (void*)&lin_w, (void*)&lin_b, (void*)&gcn_w, (void*)&gcn_b,
                      (void*)&r1_w, (void*)&r1_b, (void*)&r2_w, (void*)&r2_b,
                      (void*)&out, (void*)&q0, (void*)&q1, (void*)&q2, (void*)&p3,
                      (void*)&packed, (void*)&offs, (void*)&deg, (void*)&dinv,
                      (void*)&gcursor, (void*)&S, (void*)&chainv, (void*)&csr,
                      (void*)&N, (void*)&E };
    hipLaunchCooperativeKernel(fused, dim3(s_grid), dim3(BLK), kargs, 0, stream);
}

// Round 2
// 188.375 us; speedup vs baseline: 6.0344x; 6.0344x over previous
//
#include <hip/hip_runtime.h>
#include <math.h>

#define NGRAPH 32
#define CAP 10240        // edge capacity per bucket (mean ~8160 + pad<=768, +14 sigma)
#define EPT 16           // edges per thread in k_part
#define EPB (256 * EPT)  // 4096 edges per partition block
#define BLK 256
#define HOPGRID 784      // grid-stride hop blocks (~3/CU)

// ---------------- partition edges into fixed-capacity bucket ranges ----------------
// staged word: (bucket << 24) | (src << 8) | (dst & 255)   [src < 65536]
// block nchunk (the extra last block) instead computes the weight-chain vectors,
// overlapping the chain matmul with edge partitioning (result used only by k_mlp).
__global__ __launch_bounds__(256) void k_part_chain(
        const int* __restrict__ src, const int* __restrict__ dst,
        int* __restrict__ gcursor, unsigned int* __restrict__ packed, int E, int nchunk,
        const float* __restrict__ lin_w, const float* __restrict__ lin_b,
        const float* __restrict__ gcn_w, const float* __restrict__ gcn_b,
        float* __restrict__ chainv) {
    __shared__ union {
        struct { unsigned int ldsbuf[EPB]; int hist[256], lofs[256], lcur[256], base[256]; } p;
        struct { float v4[512]; } c;
    } sm;
    int tid = threadIdx.x;

    if ((int)blockIdx.x == nchunk) {
        // ---- weight chain: 4 vectors of 128 through 3 layers (validated in R1) ----
        float* v4 = sm.c.v4;
        int j = tid & 127, gg = tid >> 7;   // gg in {0,1}; thread owns vecs {gg, gg+2}
        if (tid < 128) {
            v4[tid]       = lin_w[tid];
            v4[128 + tid] = lin_b[tid];
            v4[256 + tid] = gcn_b[tid];        // b1
            v4[384 + tid] = gcn_b[128 + tid];  // b2
        }
        __syncthreads();
        for (int l = 0; l < 3; l++) {
            const float* W = gcn_w + l * 128 * 128;
            float a0 = 0.f, a1 = 0.f;
            for (int k0 = 0; k0 < 128; k0 += 16) {   // 16 loads in flight per batch
                float wreg[16];
#pragma unroll
                for (int t = 0; t < 16; t++) wreg[t] = W[(k0 + t) * 128 + j];
#pragma unroll
                for (int t = 0; t < 16; t++) {
                    a0 += v4[gg * 128 + k0 + t] * wreg[t];
                    a1 += v4[(gg + 2) * 128 + k0 + t] * wreg[t];
                }
            }
            __syncthreads();
            v4[gg * 128 + j] = a0;             // vec0 (w-chain), vec1 (b-chain): always
            bool upd = (gg == 0) ? (l >= 1) : (l >= 2);  // vec2 from l>=1, vec3 from l>=2
            if (upd) v4[(gg + 2) * 128 + j] = a1;
            __syncthreads();
        }
        chainv[tid]       = v4[tid];
        chainv[256 + tid] = v4[256 + tid];
        return;
    }

    // ---- edge partition: exactly one 4096-edge chunk per block ----
    int e0 = blockIdx.x * EPB;
    sm.p.hist[tid] = 0;
    __syncthreads();
    int d_[EPT], s_[EPT];
#pragma unroll
    for (int c = 0; c < EPT / 4; c++) {
        int e = e0 + c * 1024 + (tid << 2);
        if (e + 3 < E) {
            int4 dv = *(const int4*)&dst[e];
            int4 sv = *(const int4*)&src[e];
            d_[4*c+0] = dv.x; d_[4*c+1] = dv.y; d_[4*c+2] = dv.z; d_[4*c+3] = dv.w;
            s_[4*c+0] = sv.x; s_[4*c+1] = sv.y; s_[4*c+2] = sv.z; s_[4*c+3] = sv.w;
            atomicAdd(&sm.p.hist[dv.x >> 8], 1);
            atomicAdd(&sm.p.hist[dv.y >> 8], 1);
            atomicAdd(&sm.p.hist[dv.z >> 8], 1);
            atomicAdd(&sm.p.hist[dv.w >> 8], 1);
        } else {
#pragma unroll
            for (int k = 0; k < 4; k++) {
                int ee = e + k;
                if (ee < E) {
                    d_[4*c+k] = dst[ee]; s_[4*c+k] = src[ee];
                    atomicAdd(&sm.p.hist[d_[4*c+k] >> 8], 1);
                } else {
                    d_[4*c+k] = -1;
                }
            }
        }
    }
    __syncthreads();
    int v = sm.p.hist[tid];
    sm.p.lofs[tid] = v;
    __syncthreads();
    for (int off = 1; off < 256; off <<= 1) {
        int t = (tid >= off) ? sm.p.lofs[tid - off] : 0;
        __syncthreads();
        sm.p.lofs[tid] += t;
        __syncthreads();
    }
    int total = sm.p.lofs[255];
    int excl  = sm.p.lofs[tid] - v;
    __syncthreads();               // all reads of lofs done before overwrite
    sm.p.lofs[tid] = excl;
    sm.p.lcur[tid] = excl;
    if (v > 0) sm.p.base[tid] = tid * CAP + atomicAdd(&gcursor[tid], v);
    __syncthreads();
#pragma unroll
    for (int c = 0; c < EPT; c++) {
        int dd = d_[c];
        if (dd >= 0) {
            int bk = dd >> 8;
            int slot = atomicAdd(&sm.p.lcur[bk], 1);
            sm.p.ldsbuf[slot] = ((unsigned int)bk << 24) | ((unsigned int)s_[c] << 8)
                              | (unsigned int)(dd & 255);
        }
    }
    __syncthreads();
    for (int i = tid; i < total; i += BLK) {
        unsigned int w = sm.p.ldsbuf[i];
        int bk = w >> 24;
        packed[sm.p.base[bk] + (i - sm.p.lofs[bk])] = w & 0xFFFFFFu;
    }
}

// ---------------- per-bucket CSR build (pad-to-4, sentinel-filled) + deg/dinv/q0/counts ----
__global__ __launch_bounds__(256) void k_bucket(
        const unsigned int* __restrict__ packed, const int* __restrict__ gcursor,
        const float* __restrict__ x, const int* __restrict__ batch,
        int* __restrict__ offs, int* __restrict__ deg,
        float* __restrict__ dinv, float2* __restrict__ q0,
        float2* __restrict__ q1, float2* __restrict__ q2,
        unsigned short* __restrict__ csr, float* __restrict__ S, int N) {
    __shared__ unsigned int buf[CAP];     // 40 KB LDS stage: one global pass over packed
    __shared__ int cnt[256], lofs[256], lcur[256];
    __shared__ float cs[NGRAPH];
    int tid = threadIdx.x;
    int b = blockIdx.x;
    int start = b * CAP;
    int len = gcursor[b];
    cnt[tid] = 0;
    if (tid < NGRAPH) cs[tid] = 0.f;
    __syncthreads();
    for (int e = tid; e < len; e += BLK) {
        unsigned int w = packed[start + e];
        buf[e] = w;
        atomicAdd(&cnt[w & 255], 1);
    }
    __syncthreads();
    int v = cnt[tid];
    int vp = (v + 3) & ~3;          // pad each node's slot to multiple of 4
    lofs[tid] = vp;
    __syncthreads();
    for (int off = 1; off < 256; off <<= 1) {
        int t = (tid >= off) ? lofs[tid - off] : 0;
        __syncthreads();
        lofs[tid] += t;
        __syncthreads();
    }
    int excl = lofs[tid] - vp;      // multiple of 4 for every node
    lcur[tid] = excl;
    int node = b * 256 + tid;
    if (node < N) {
        deg[node] = v;
        offs[node] = start + excl;
        float dv = rsqrtf((float)(v + 1));   // +1 self loop
        dinv[node] = dv;
        q0[node] = make_float2(x[node] * dv, dv);
        atomicAdd(&cs[batch[node]], 1.f);
        for (int p = v; p < vp; p++)          // 0..3 sentinel pads -> q[N]=(0,0)
            csr[start + excl + p] = (unsigned short)N;
    }
    if (b == 0 && tid == 0) {
        q0[N] = make_float2(0.f, 0.f);
        q1[N] = make_float2(0.f, 0.f);
        q2[N] = make_float2(0.f, 0.f);
    }
    __syncthreads();
    for (int e = tid; e < len; e += BLK) {
        unsigned int w = buf[e];
        int pos = start + atomicAdd(&lcur[w & 255], 1);
        csr[pos] = (unsigned short)(w >> 8);
    }
    if (tid < NGRAPH && cs[tid] != 0.f) atomicAdd(&S[tid], cs[tid]);
}

// ---------------- one hop, 8 lanes per node, ushort4 csr loads, grid-stride ----------------
template <int WRITE_Q>
__global__ __launch_bounds__(256) void k_hop(
        const float2* __restrict__ qin, float2* __restrict__ outv,
        const unsigned short* __restrict__ csr,
        const int* __restrict__ offs, const int* __restrict__ deg,
        const float* __restrict__ dinv, int N, int ntiles) {
    int tid  = threadIdx.x;
    int lane = tid & 7;
    int sub  = tid >> 3;                  // 32 nodes per block
    for (int t = blockIdx.x; t < ntiles; t += gridDim.x) {
        int node = t * 32 + sub;
        if (node >= N) continue;
        int e = offs[node], ne = deg[node];   // e % 4 == 0; slot padded with sentinels
        float sx = 0.0f, su = 0.0f;
        for (int j = 4 * lane; j < ne; j += 32) {
            ushort4 c = *(const ushort4*)&csr[e + j];   // pad entries -> qin[N] == (0,0)
            float2 a = qin[c.x];
            float2 b = qin[c.y];
            float2 c2 = qin[c.z];
            float2 d2 = qin[c.w];
            sx += (a.x + b.x) + (c2.x + d2.x);
            su += (a.y + b.y) + (c2.y + d2.y);
        }
#pragma unroll
        for (int m = 4; m > 0; m >>= 1) {
            sx += __shfl_xor(sx, m);
            su += __shfl_xor(su, m);
        }
        if (lane == 0) {
            float2 qs = qin[node];
            float dv = dinv[node];
            float px = dv * (sx + qs.x), pu = dv * (su + qs.y);
            if (WRITE_Q) outv[node] = make_float2(px * dv, pu * dv);
            else         outv[node] = make_float2(px, pu);
        }
    }
}

// ---------------- readout: hop3 fused in (gather q2 directly) + per-graph MLP ----------------
__global__ __launch_bounds__(256) void k_mlp(
        const float* __restrict__ S, const float* __restrict__ chainv,
        const float2* __restrict__ q1, const float2* __restrict__ q2,
        const unsigned short* __restrict__ csr,
        const int* __restrict__ offs, const int* __restrict__ deg,
        const float* __restrict__ dinv, const float* __restrict__ gcn_b,
        const float* __restrict__ r1_w, const float* __restrict__ r1_b,
        const float* __restrict__ r2_w, const float* __restrict__ r2_b,
        float* __restrict__ out, int N) {
    __shared__ float rw[128 * 128];       // 64 KB
    __shared__ float pl[128], red[128];
    __shared__ float cnts[NGRAPH];
    __shared__ float r4[4 * 128];
    int tid = threadIdx.x;
    int g = blockIdx.x;
    {
        const float4* Rg = (const float4*)r1_w;
        float4* Rs = (float4*)rw;
#pragma unroll
        for (int i = 0; i < 16; i++) Rs[tid + i * 256] = Rg[tid + i * 256];
    }
    if (tid < NGRAPH) cnts[tid] = S[tid];
    __syncthreads();
    int r0 = 0;
    for (int i = 0; i < g; i++) r0 += (int)cnts[i];
    int cnt = (int)cnts[g];
    int r1e = r0 + cnt;
    float su1 = 0.f, su2 = 0.f, su3 = 0.f, sv3 = 0.f;
    for (int n = r0 + tid; n < r1e; n += BLK) {
        float dv = dinv[n];
        float inv = 1.0f / dv;
        su1 += q1[n].y * inv;
        float2 q2n = q2[n];
        su2 += q2n.y * inv;
        // ---- hop3 on the fly: p3 = dv * (self + sum of neighbors' q2) ----
        int e = offs[n], ne = deg[n];
        float sx = q2n.x, su = q2n.y;     // self loop term
        for (int j = 0; j < ne; j += 4) {
            ushort4 c = *(const ushort4*)&csr[e + j];   // sentinels -> q2[N]==(0,0)
            float2 a = q2[c.x];
            float2 b = q2[c.y];
            float2 c2 = q2[c.z];
            float2 d2 = q2[c.w];
            sx += (a.x + b.x) + (c2.x + d2.x);
            su += (a.y + b.y) + (c2.y + d2.y);
        }
        sv3 += dv * sx;
        su3 += dv * su;
    }
#pragma unroll
    for (int m = 32; m > 0; m >>= 1) {
        su1 += __shfl_xor(su1, m);
        su2 += __shfl_xor(su2, m);
        su3 += __shfl_xor(su3, m);
        sv3 += __shfl_xor(sv3, m);
    }
    int wv = tid >> 6;
    if ((tid & 63) == 0) {
        r4[wv] = su1; r4[4 + wv] = su2; r4[8 + wv] = su3; r4[12 + wv] = sv3;
    }
    __syncthreads();
    su1 = r4[0] + r4[1] + r4[2] + r4[3];
    su2 = r4[4] + r4[5] + r4[6] + r4[7];
    su3 = r4[8] + r4[9] + r4[10] + r4[11];
    sv3 = r4[12] + r4[13] + r4[14] + r4[15];
    const float* b3 = gcn_b + 2 * 128;
    if (tid < 128)
        pl[tid] = sv3 * chainv[tid] + su3 * chainv[128 + tid] + su2 * chainv[256 + tid]
                + su1 * chainv[384 + tid] + (float)cnt * b3[tid];
    __syncthreads();
    int j = tid & 127, half = tid >> 7;
    float acc = 0.f;
#pragma unroll 8
    for (int kk = 0; kk < 64; kk++) {
        int k = half * 64 + kk;
        acc += pl[k] * rw[k * 128 + j];
    }
    r4[half * 128 + j] = acc;
    __syncthreads();
    if (tid < 128) {
        float a = r4[tid] + r4[128 + tid] + r1_b[tid];
        red[tid] = tanhf(a) * r2_w[tid];
    }
    __syncthreads();
    for (int sft = 64; sft > 0; sft >>= 1) {
        if (tid < sft) red[tid] += red[tid + sft];
        __syncthreads();
    }
    if (tid == 0) out[g] = red[0] + r2_b[0];
}

extern "C" void kernel_launch(void* const* d_in, const int* in_sizes, int n_in,
                              void* d_out, int out_size, void* d_ws, size_t ws_size,
                              hipStream_t stream) {
    const float* x     = (const float*)d_in[0];
    const int*   eidx  = (const int*)d_in[1];
    const int*   batch = (const int*)d_in[2];
    const float* lin_w = (const float*)d_in[3];
    const float* lin_b = (const float*)d_in[4];
    const float* gcn_w = (const float*)d_in[5];
    const float* gcn_b = (const float*)d_in[6];
    const float* r1_w  = (const float*)d_in[7];
    const float* r1_b  = (const float*)d_in[8];
    const float* r2_w  = (const float*)d_in[9];
    const float* r2_b  = (const float*)d_in[10];

    const int N = in_sizes[0];
    const int E = in_sizes[1] / 2;
    const int* src = eidx;
    const int* dst = eidx + E;
    const int NB = (N + 255) / 256;  // 196 buckets

    // workspace layout: 8B-aligned types first, 4B, then 2B csr last
    char* w = (char*)d_ws;
    float2* q0      = (float2*)w; w += (size_t)(N + 2) * 8;
    float2* q1      = (float2*)w; w += (size_t)(N + 2) * 8;
    float2* q2      = (float2*)w; w += (size_t)(N + 2) * 8;
    unsigned int* packed = (unsigned int*)w; w += (size_t)256 * CAP * 4;
    int*    offs    = (int*)w;    w += (size_t)N * 4;
    int*    deg     = (int*)w;    w += (size_t)N * 4;
    float*  dinv    = (float*)w;  w += (size_t)N * 4;
    int*    gcursor = (int*)w;    w += 256 * 4;
    float*  S       = (float*)w;  w += 64 * 4;
    float*  chainv  = (float*)w;  w += 512 * 4;
    unsigned short* csr = (unsigned short*)w; w += (size_t)256 * CAP * 2 + 256;

    // single memset covers gcursor (1024 B) + S (256 B), contiguous
    hipMemsetAsync(gcursor, 0, 256 * 4 + 64 * 4, stream);

    const int nchunk = (E + EPB - 1) / EPB;   // 391
    k_part_chain<<<nchunk + 1, 256, 0, stream>>>(src, dst, gcursor, packed, E, nchunk,
                                                 lin_w, lin_b, gcn_w, gcn_b, chainv);
    k_bucket<<<NB, 256, 0, stream>>>(packed, gcursor, x, batch, offs, deg, dinv,
                                     q0, q1, q2, csr, S, N);

    const int ntiles = (N + 31) / 32;         // 1563
    k_hop<1><<<HOPGRID, 256, 0, stream>>>(q0, q1, csr, offs, deg, dinv, N, ntiles);
    k_hop<1><<<HOPGRID, 256, 0, stream>>>(q1, q2, csr, offs, deg, dinv, N, ntiles);

    k_mlp<<<NGRAPH, 256, 0, stream>>>(S, chainv, q1, q2, csr, offs, deg, dinv, gcn_b,
                                      r1_w, r1_b, r2_w, r2_b, (float*)d_out, N);
}

// Round 3
// 155.674 us; speedup vs baseline: 7.3019x; 1.2101x over previous
//
#include <hip/hip_runtime.h>
#include <math.h>

#define NGRAPH 32
#define CAP 10240        // edge capacity per bucket (mean ~8160 + pad<=7/node, +13 sigma)
#define EPT 8            // edges per thread in k_part (782 blocks ~ 3/CU)
#define EPB (256 * EPT)  // 2048 edges per partition block
#define BLK 256

// ---- block-wide exclusive scan over 256 threads, 2 barriers (shfl-based) ----
__device__ __forceinline__ int block_scan_excl(int v, int tid, int* wsum, int& total) {
    int x = v;
#pragma unroll
    for (int d = 1; d < 64; d <<= 1) {
        int t = __shfl_up(x, d);
        if ((tid & 63) >= d) x += t;
    }
    if ((tid & 63) == 63) wsum[tid >> 6] = x;   // wave inclusive totals
    __syncthreads();
    if (tid == 0) {
        int a = 0;
#pragma unroll
        for (int i = 0; i < 4; i++) { int t = wsum[i]; wsum[i] = a; a += t; }
        wsum[4] = a;
    }
    __syncthreads();
    total = wsum[4];
    return x - v + wsum[tid >> 6];
}

// ---------------- partition edges into fixed-capacity bucket ranges ----------------
// staged word: (bucket << 24) | (src << 8) | (dst & 255)   [src < 65536]
// extra last block computes the weight-chain vectors concurrently (used only by k_mlp).
__global__ __launch_bounds__(256) void k_part_chain(
        const int* __restrict__ src, const int* __restrict__ dst,
        int* __restrict__ gcursor, unsigned int* __restrict__ packed, int E, int nchunk,
        const float* __restrict__ lin_w, const float* __restrict__ lin_b,
        const float* __restrict__ gcn_w, const float* __restrict__ gcn_b,
        float* __restrict__ chainv) {
    __shared__ union {
        struct { unsigned int ldsbuf[EPB]; int hist[256], lofs[256], lcur[256], base[256], wsum[5]; } p;
        struct { float v4[512]; } c;
    } sm;
    int tid = threadIdx.x;

    if ((int)blockIdx.x == nchunk) {
        // ---- weight chain: 4 vectors of 128 through 3 layers (validated R1/R2) ----
        float* v4 = sm.c.v4;
        int j = tid & 127, gg = tid >> 7;   // gg in {0,1}; thread owns vecs {gg, gg+2}
        if (tid < 128) {
            v4[tid]       = lin_w[tid];
            v4[128 + tid] = lin_b[tid];
            v4[256 + tid] = gcn_b[tid];        // b1
            v4[384 + tid] = gcn_b[128 + tid];  // b2
        }
        __syncthreads();
        for (int l = 0; l < 3; l++) {
            const float* W = gcn_w + l * 128 * 128;
            float a0 = 0.f, a1 = 0.f;
            for (int k0 = 0; k0 < 128; k0 += 16) {   // 16 loads in flight per batch
                float wreg[16];
#pragma unroll
                for (int t = 0; t < 16; t++) wreg[t] = W[(k0 + t) * 128 + j];
#pragma unroll
                for (int t = 0; t < 16; t++) {
                    a0 += v4[gg * 128 + k0 + t] * wreg[t];
                    a1 += v4[(gg + 2) * 128 + k0 + t] * wreg[t];
                }
            }
            __syncthreads();
            v4[gg * 128 + j] = a0;             // vec0 (w-chain), vec1 (b-chain): always
            bool upd = (gg == 0) ? (l >= 1) : (l >= 2);  // vec2 from l>=1, vec3 from l>=2
            if (upd) v4[(gg + 2) * 128 + j] = a1;
            __syncthreads();
        }
        chainv[tid]       = v4[tid];
        chainv[256 + tid] = v4[256 + tid];
        return;
    }

    // ---- edge partition: one 2048-edge chunk per block ----
    int e0 = blockIdx.x * EPB;
    sm.p.hist[tid] = 0;
    __syncthreads();
    int d_[EPT], s_[EPT];
#pragma unroll
    for (int c = 0; c < EPT / 4; c++) {
        int e = e0 + c * 1024 + (tid << 2);
        if (e + 3 < E) {
            int4 dv = *(const int4*)&dst[e];
            int4 sv = *(const int4*)&src[e];
            d_[4*c+0] = dv.x; d_[4*c+1] = dv.y; d_[4*c+2] = dv.z; d_[4*c+3] = dv.w;
            s_[4*c+0] = sv.x; s_[4*c+1] = sv.y; s_[4*c+2] = sv.z; s_[4*c+3] = sv.w;
            atomicAdd(&sm.p.hist[dv.x >> 8], 1);
            atomicAdd(&sm.p.hist[dv.y >> 8], 1);
            atomicAdd(&sm.p.hist[dv.z >> 8], 1);
            atomicAdd(&sm.p.hist[dv.w >> 8], 1);
        } else {
#pragma unroll
            for (int k = 0; k < 4; k++) {
                int ee = e + k;
                if (ee < E) {
                    d_[4*c+k] = dst[ee]; s_[4*c+k] = src[ee];
                    atomicAdd(&sm.p.hist[d_[4*c+k] >> 8], 1);
                } else {
                    d_[4*c+k] = -1;
                }
            }
        }
    }
    __syncthreads();
    int v = sm.p.hist[tid];
    int total;
    int excl = block_scan_excl(v, tid, sm.p.wsum, total);
    sm.p.lofs[tid] = excl;
    sm.p.lcur[tid] = excl;
    if (v > 0) sm.p.base[tid] = tid * CAP + atomicAdd(&gcursor[tid], v);
    __syncthreads();
#pragma unroll
    for (int c = 0; c < EPT; c++) {
        int dd = d_[c];
        if (dd >= 0) {
            int bk = dd >> 8;
            int slot = atomicAdd(&sm.p.lcur[bk], 1);
            sm.p.ldsbuf[slot] = ((unsigned int)bk << 24) | ((unsigned int)s_[c] << 8)
                              | (unsigned int)(dd & 255);
        }
    }
    __syncthreads();
    for (int i = tid; i < total; i += BLK) {
        unsigned int w = sm.p.ldsbuf[i];
        int bk = w >> 24;
        packed[sm.p.base[bk] + (i - sm.p.lofs[bk])] = w & 0xFFFFFFu;
    }
}

// ---------------- per-bucket CSR build fully in LDS (pad-to-8, sentinels), coalesced out ----
__global__ __launch_bounds__(256) void k_bucket(
        const unsigned int* __restrict__ packed, const int* __restrict__ gcursor,
        const float* __restrict__ x, const int* __restrict__ batch,
        int* __restrict__ offs, int* __restrict__ deg,
        float* __restrict__ dinv, float2* __restrict__ q0,
        float2* __restrict__ q1, float2* __restrict__ q2,
        unsigned short* __restrict__ csr, float* __restrict__ S, int N) {
    __shared__ unsigned int buf[CAP];                  // 40 KB: single global pass
    __shared__ __align__(16) unsigned short lcsr[CAP]; // 20 KB: CSR staged in LDS
    __shared__ int cnt[256], lcur[256], wsum[5];
    __shared__ float cs[NGRAPH];
    int tid = threadIdx.x;
    int b = blockIdx.x;
    int start = b * CAP;
    int len = gcursor[b];
    cnt[tid] = 0;
    if (tid < NGRAPH) cs[tid] = 0.f;
    __syncthreads();
    for (int e = tid; e < len; e += BLK) {
        unsigned int w = packed[start + e];
        buf[e] = w;
        atomicAdd(&cnt[w & 255], 1);
    }
    __syncthreads();
    int v = cnt[tid];
    int vp = (v + 7) & ~7;          // pad each node's slot to multiple of 8
    int total;
    int excl = block_scan_excl(vp, tid, wsum, total);  // multiple of 8 for every node
    lcur[tid] = excl;
    int node = b * 256 + tid;
    if (node < N) {
        deg[node] = v;
        offs[node] = start + excl;
        float dv = rsqrtf((float)(v + 1));   // +1 self loop
        dinv[node] = dv;
        q0[node] = make_float2(x[node] * dv, dv);
        atomicAdd(&cs[batch[node]], 1.f);
        for (int p = v; p < vp; p++)          // 0..7 sentinel pads -> q[N]=(0,0)
            lcsr[excl + p] = (unsigned short)N;
    }
    if (b == 0 && tid == 0) {
        q0[N] = make_float2(0.f, 0.f);
        q1[N] = make_float2(0.f, 0.f);
        q2[N] = make_float2(0.f, 0.f);
    }
    __syncthreads();
    for (int e = tid; e < len; e += BLK) {
        unsigned int w = buf[e];
        lcsr[atomicAdd(&lcur[w & 255], 1)] = (unsigned short)(w >> 8);
    }
    if (tid < NGRAPH && cs[tid] != 0.f) atomicAdd(&S[tid], cs[tid]);
    __syncthreads();
    // coalesced copy-out: total entries, multiple of 8 (16 B chunks)
    const uint4* ls = (const uint4*)lcsr;
    uint4* gs = (uint4*)&csr[start];        // start*2 bytes, multiple of 16
    for (int i = tid; i < (total >> 3); i += BLK) gs[i] = ls[i];
}

// ---------------- one hop, 4 lanes per node, 8 gathers in flight per lane ----------------
template <int WRITE_Q>
__global__ __launch_bounds__(256) void k_hop(
        const float2* __restrict__ qin, float2* __restrict__ outv,
        const unsigned short* __restrict__ csr,
        const int* __restrict__ offs, const int* __restrict__ deg,
        const float* __restrict__ dinv, int N) {
    int tid  = threadIdx.x;
    int lane = tid & 3;
    int node = blockIdx.x * 64 + (tid >> 2);
    if (node >= N) return;
    int e = offs[node], ne = deg[node];   // e % 8 == 0; slot padded with sentinels
    float sx = 0.0f, su = 0.0f;
    for (int j = 8 * lane; j < ne; j += 32) {
        ushort4 c0 = *(const ushort4*)&csr[e + j];       // pads -> qin[N] == (0,0)
        ushort4 c1 = *(const ushort4*)&csr[e + j + 4];
        float2 a0 = qin[c0.x], a1 = qin[c0.y], a2 = qin[c0.z], a3 = qin[c0.w];
        float2 b0 = qin[c1.x], b1 = qin[c1.y], b2 = qin[c1.z], b3 = qin[c1.w];
        sx += ((a0.x + a1.x) + (a2.x + a3.x)) + ((b0.x + b1.x) + (b2.x + b3.x));
        su += ((a0.y + a1.y) + (a2.y + a3.y)) + ((b0.y + b1.y) + (b2.y + b3.y));
    }
#pragma unroll
    for (int m = 2; m > 0; m >>= 1) {
        sx += __shfl_xor(sx, m);
        su += __shfl_xor(su, m);
    }
    if (lane == 0) {
        float2 qs = qin[node];
        float dv = dinv[node];
        float px = dv * (sx + qs.x), pu = dv * (su + qs.y);
        if (WRITE_Q) outv[node] = make_float2(px * dv, pu * dv);
        else         outv[node] = make_float2(px, pu);
    }
}

// ---------------- readout: per-graph sums + MLP (R0-proven form) ----------------
__global__ __launch_bounds__(256) void k_mlp(
        const float* __restrict__ S, const float* __restrict__ chainv,
        const float2* __restrict__ q1, const float2* __restrict__ q2,
        const float2* __restrict__ p3, const float* __restrict__ dinv,
        const float* __restrict__ gcn_b,
        const float* __restrict__ r1_w, const float* __restrict__ r1_b,
        const float* __restrict__ r2_w, const float* __restrict__ r2_b,
        float* __restrict__ out, int N) {
    __shared__ float rw[128 * 128];       // 64 KB
    __shared__ float pl[128], red[128];
    __shared__ float cnts[NGRAPH];
    __shared__ float r4[4 * 128];
    int tid = threadIdx.x;
    int g = blockIdx.x;
    {
        const float4* Rg = (const float4*)r1_w;
        float4* Rs = (float4*)rw;
#pragma unroll
        for (int i = 0; i < 16; i++) Rs[tid + i * 256] = Rg[tid + i * 256];
    }
    if (tid < NGRAPH) cnts[tid] = S[tid];
    __syncthreads();
    int r0 = 0;
    for (int i = 0; i < g; i++) r0 += (int)cnts[i];
    int cnt = (int)cnts[g];
    int r1e = r0 + cnt;
    float su1 = 0.f, su2 = 0.f, su3 = 0.f, sv3 = 0.f;
    for (int n = r0 + tid; n < r1e; n += BLK) {
        float inv = 1.0f / dinv[n];
        su1 += q1[n].y * inv;
        su2 += q2[n].y * inv;
        float2 p = p3[n];
        su3 += p.y; sv3 += p.x;
    }
#pragma unroll
    for (int m = 32; m > 0; m >>= 1) {
        su1 += __shfl_xor(su1, m);
        su2 += __shfl_xor(su2, m);
        su3 += __shfl_xor(su3, m);
        sv3 += __shfl_xor(sv3, m);
    }
    int wv = tid >> 6;
    if ((tid & 63) == 0) {
        r4[wv] = su1; r4[4 + wv] = su2; r4[8 + wv] = su3; r4[12 + wv] = sv3;
    }
    __syncthreads();
    su1 = r4[0] + r4[1] + r4[2] + r4[3];
    su2 = r4[4] + r4[5] + r4[6] + r4[7];
    su3 = r4[8] + r4[9] + r4[10] + r4[11];
    sv3 = r4[12] + r4[13] + r4[14] + r4[15];
    const float* b3 = gcn_b + 2 * 128;
    if (tid < 128)
        pl[tid] = sv3 * chainv[tid] + su3 * chainv[128 + tid] + su2 * chainv[256 + tid]
                + su1 * chainv[384 + tid] + (float)cnt * b3[tid];
    __syncthreads();
    int j = tid & 127, half = tid >> 7;
    float acc = 0.f;
#pragma unroll 8
    for (int kk = 0; kk < 64; kk++) {
        int k = half * 64 + kk;
        acc += pl[k] * rw[k * 128 + j];
    }
    r4[half * 128 + j] = acc;
    __syncthreads();
    if (tid < 128) {
        float a = r4[tid] + r4[128 + tid] + r1_b[tid];
        red[tid] = tanhf(a) * r2_w[tid];
    }
    __syncthreads();
    for (int sft = 64; sft > 0; sft >>= 1) {
        if (tid < sft) red[tid] += red[tid + sft];
        __syncthreads();
    }
    if (tid == 0) out[g] = red[0] + r2_b[0];
}

extern "C" void kernel_launch(void* const* d_in, const int* in_sizes, int n_in,
                              void* d_out, int out_size, void* d_ws, size_t ws_size,
                              hipStream_t stream) {
    const float* x     = (const float*)d_in[0];
    const int*   eidx  = (const int*)d_in[1];
    const int*   batch = (const int*)d_in[2];
    const float* lin_w = (const float*)d_in[3];
    const float* lin_b = (const float*)d_in[4];
    const float* gcn_w = (const float*)d_in[5];
    const float* gcn_b = (const float*)d_in[6];
    const float* r1_w  = (const float*)d_in[7];
    const float* r1_b  = (const float*)d_in[8];
    const float* r2_w  = (const float*)d_in[9];
    const float* r2_b  = (const float*)d_in[10];

    const int N = in_sizes[0];
    const int E = in_sizes[1] / 2;
    const int* src = eidx;
    const int* dst = eidx + E;
    const int NB = (N + 255) / 256;  // 196 buckets

    // workspace layout: 8B-aligned types first, 4B, then 2B csr last (csr base 16B-aligned)
    char* w = (char*)d_ws;
    float2* q0      = (float2*)w; w += (size_t)(N + 2) * 8;
    float2* q1      = (float2*)w; w += (size_t)(N + 2) * 8;
    float2* q2      = (float2*)w; w += (size_t)(N + 2) * 8;
    float2* p3      = (float2*)w; w += (size_t)(N + 2) * 8;
    unsigned int* packed = (unsigned int*)w; w += (size_t)256 * CAP * 4;
    int*    offs    = (int*)w;    w += (size_t)N * 4;
    int*    deg     = (int*)w;    w += (size_t)N * 4;
    float*  dinv    = (float*)w;  w += (size_t)N * 4;
    int*    gcursor = (int*)w;    w += 256 * 4;
    float*  S       = (float*)w;  w += 64 * 4;
    float*  chainv  = (float*)w;  w += 512 * 4;
    unsigned short* csr = (unsigned short*)w; w += (size_t)256 * CAP * 2 + 256;

    // single memset covers gcursor (1024 B) + S (256 B), contiguous
    hipMemsetAsync(gcursor, 0, 256 * 4 + 64 * 4, stream);

    const int nchunk = (E + EPB - 1) / EPB;   // 782
    k_part_chain<<<nchunk + 1, 256, 0, stream>>>(src, dst, gcursor, packed, E, nchunk,
                                                 lin_w, lin_b, gcn_w, gcn_b, chainv);
    k_bucket<<<NB, 256, 0, stream>>>(packed, gcursor, x, batch, offs, deg, dinv,
                                     q0, q1, q2, csr, S, N);

    const int hop_blocks = (N + 63) / 64;     // 782
    k_hop<1><<<hop_blocks, 256, 0, stream>>>(q0, q1, csr, offs, deg, dinv, N);
    k_hop<1><<<hop_blocks, 256, 0, stream>>>(q1, q2, csr, offs, deg, dinv, N);
    k_hop<0><<<hop_blocks, 256, 0, stream>>>(q2, p3, csr, offs, deg, dinv, N);

    k_mlp<<<NGRAPH, 256, 0, stream>>>(S, chainv, q1, q2, p3, dinv, gcn_b,
                                      r1_w, r1_b, r2_w, r2_b, (float*)d_out, N);
}